// Round 3
// baseline (184.698 us; speedup 1.0000x reference)
//
#include <hip/hip_runtime.h>
#include <hip/hip_bf16.h>

// CorrelationNetwork fused kernels for MI355X (gfx950) — round 3.
// R2 post-mortem: the hidden bottleneck was the LDS pipe (~18us/CU: At
// write+read + 512 ds_swizzle/block epilogue) + barrier serialization.
// R3: swap MFMA operand roles -> D[w2col][h1row]. h1 frags are built
// directly in registers (B-operand layout), W2^T frags come from L1,
// epilogue reduction is in-lane over regs + 2 shfl. ZERO LDS, ZERO
// barriers in the main kernel; b2 folded into acc init.

typedef __bf16 bf16x8 __attribute__((ext_vector_type(8)));
typedef float f32x4 __attribute__((ext_vector_type(4)));

#define B_SZ 128
#define N_SZ 64
#define H_SZ 128

union FragU {
  bf16x8 v;
  __hip_bfloat162 h[4];
};

__device__ __forceinline__ unsigned pack_bf16x2(float lo, float hi) {
  unsigned a = __float_as_uint(lo);
  unsigned b = __float_as_uint(hi);
  a += 0x7fffu + ((a >> 16) & 1u);   // RNE round to bf16
  b += 0x7fffu + ((b >> 16) & 1u);
  return (a >> 16) | (b & 0xffff0000u);
}

// ---- setup: blocks 0..2047 prepass (4 bn-rows each), 2048..2111 W2->W2T bf16,
//      block 2112 softmax(mixing_weights)
__global__ __launch_bounds__(256) void setup_kernel(
    const float* __restrict__ af, const float* __restrict__ W1,
    const float* __restrict__ b1, const float* __restrict__ W2,
    const float* __restrict__ mw, float* __restrict__ AiP,
    float* __restrict__ Aj, unsigned short* __restrict__ W2T,
    float* __restrict__ outw)
{
  const int blk = blockIdx.x;
  const int tid = threadIdx.x;

  if (blk < 2048) {
    // prepass: AiP[bn,h] = sum_f f[bn,f]*W1[f,h] + b1[h]; Aj via W1[64+f]
    __shared__ float fl[4 * 64];
    const int bn0 = blk << 2;
    fl[tid] = af[((bn0 + (tid >> 6)) << 7) + (tid & 63)];
    __syncthreads();
    const int h    = tid & 127;
    const int half = tid >> 7;                 // 0 -> Ai, 1 -> Aj
    const float* Wp = W1 + ((half << 6) << 7) + h;
    float acc0 = 0.f, acc1 = 0.f, acc2 = 0.f, acc3 = 0.f;
#pragma unroll
    for (int fq = 0; fq < 16; ++fq) {
      const float w0 = Wp[(fq * 4 + 0) << 7];
      const float w1v = Wp[(fq * 4 + 1) << 7];
      const float w2v = Wp[(fq * 4 + 2) << 7];
      const float w3v = Wp[(fq * 4 + 3) << 7];
      const float4 f0 = *(const float4*)&fl[0 * 64 + (fq << 2)];
      const float4 f1 = *(const float4*)&fl[1 * 64 + (fq << 2)];
      const float4 f2 = *(const float4*)&fl[2 * 64 + (fq << 2)];
      const float4 f3 = *(const float4*)&fl[3 * 64 + (fq << 2)];
      acc0 = fmaf(f0.x, w0, fmaf(f0.y, w1v, fmaf(f0.z, w2v, fmaf(f0.w, w3v, acc0))));
      acc1 = fmaf(f1.x, w0, fmaf(f1.y, w1v, fmaf(f1.z, w2v, fmaf(f1.w, w3v, acc1))));
      acc2 = fmaf(f2.x, w0, fmaf(f2.y, w1v, fmaf(f2.z, w2v, fmaf(f2.w, w3v, acc2))));
      acc3 = fmaf(f3.x, w0, fmaf(f3.y, w1v, fmaf(f3.z, w2v, fmaf(f3.w, w3v, acc3))));
    }
    if (half == 0) {
      const float bb = b1[h];
      AiP[((bn0 + 0) << 7) + h] = acc0 + bb;
      AiP[((bn0 + 1) << 7) + h] = acc1 + bb;
      AiP[((bn0 + 2) << 7) + h] = acc2 + bb;
      AiP[((bn0 + 3) << 7) + h] = acc3 + bb;
    } else {
      Aj[((bn0 + 0) << 7) + h] = acc0;
      Aj[((bn0 + 1) << 7) + h] = acc1;
      Aj[((bn0 + 2) << 7) + h] = acc2;
      Aj[((bn0 + 3) << 7) + h] = acc3;
    }
  } else if (blk < 2112) {
    // W2 (128x128, k-major) -> W2T (n-major) bf16
    int idx = ((blk - 2048) << 8) + tid;       // 0..16383
    int k = idx >> 7, n = idx & 127;
    unsigned u = __float_as_uint(W2[idx]);
    u += 0x7fffu + ((u >> 16) & 1u);
    W2T[(n << 7) + k] = (unsigned short)(u >> 16);
  } else {
    // softmax over 64 mixing weights
    if (tid < 64) {
      float v = mw[tid];
      float m = v;
      for (int off = 32; off > 0; off >>= 1) m = fmaxf(m, __shfl_xor(m, off));
      float e = expf(v - m);
      float s = e;
      for (int off = 32; off > 0; off >>= 1) s += __shfl_xor(s, off);
      outw[tid] = e / s;
    }
  }
}

// ---- main kernel: one wave = one independent 32-row x 128-col strip.
// Global wave id gw: b = gw>>7, strip s = gw&127, i = s>>1, j0 = (s&1)*32.
// rows: j = j0 + 16*tn + c (c = lane&15), same i for the whole strip.
// MFMA with swapped roles: D = W2frag(A) * h1frag(B) -> D[m=w2col][n=h1row].
// C-layout (verified m89/m91): w2col = 16*tm + 4*g + p, h1row-local = c.
// Epilogue: in-lane sum over (tm,p), then shfl_xor 16/32 over g. No LDS.
__global__ __launch_bounds__(256) void corr_kernel(
    const float* __restrict__ AiP, const float* __restrict__ Aj,
    const unsigned short* __restrict__ W2T,
    const float* __restrict__ b2, const float* __restrict__ w3,
    const float* __restrict__ b3, float* __restrict__ out)
{
  const int tid  = threadIdx.x;
  const int lane = tid & 63;
  const int gw   = (blockIdx.x << 2) + (tid >> 6);
  const int b    = gw >> 7;
  const int s    = gw & 127;
  const int i    = s >> 1;
  const int j0   = (s & 1) << 5;
  const int c = lane & 15, g = lane >> 4;

  // per-lane base pointers (k-offset kt*32 elements applied as immediates)
  const float* aip = AiP + (((b << 6) + i) << 7) + (g << 3);
  const float* aj0 = Aj + (((b << 6) + j0 + c) << 7) + (g << 3);
  const float* aj1 = aj0 + (16 << 7);
  const unsigned short* w2p = W2T + (c << 7) + (g << 3);

  // acc init = b2 broadcast (D = A*B + C): acc[tm][tn][p] <- b2[16tm+4g+p]
  f32x4 acc[8][2];
#pragma unroll
  for (int tm = 0; tm < 8; ++tm) {
    const f32x4 bq = *(const f32x4*)(b2 + (tm << 4) + (g << 2));
    acc[tm][0] = bq;
    acc[tm][1] = bq;
  }

#pragma unroll
  for (int kt = 0; kt < 4; ++kt) {
    // build two h1 B-frags in registers: rows j0+16tn+c, k = kt*32+g*8..+7
    const float4 a0 = *(const float4*)(aip + (kt << 5));
    const float4 a1 = *(const float4*)(aip + (kt << 5) + 4);
    const float4 q0 = *(const float4*)(aj0 + (kt << 5));
    const float4 q1 = *(const float4*)(aj0 + (kt << 5) + 4);
    const float4 r0 = *(const float4*)(aj1 + (kt << 5));
    const float4 r1 = *(const float4*)(aj1 + (kt << 5) + 4);

    FragU h0, h1;
    h0.h[0] = __float22bfloat162_rn(
        float2{fmaxf(a0.x + q0.x, 0.f), fmaxf(a0.y + q0.y, 0.f)});
    h0.h[1] = __float22bfloat162_rn(
        float2{fmaxf(a0.z + q0.z, 0.f), fmaxf(a0.w + q0.w, 0.f)});
    h0.h[2] = __float22bfloat162_rn(
        float2{fmaxf(a1.x + q1.x, 0.f), fmaxf(a1.y + q1.y, 0.f)});
    h0.h[3] = __float22bfloat162_rn(
        float2{fmaxf(a1.z + q1.z, 0.f), fmaxf(a1.w + q1.w, 0.f)});
    h1.h[0] = __float22bfloat162_rn(
        float2{fmaxf(a0.x + r0.x, 0.f), fmaxf(a0.y + r0.y, 0.f)});
    h1.h[1] = __float22bfloat162_rn(
        float2{fmaxf(a0.z + r0.z, 0.f), fmaxf(a0.w + r0.w, 0.f)});
    h1.h[2] = __float22bfloat162_rn(
        float2{fmaxf(a1.x + r1.x, 0.f), fmaxf(a1.y + r1.y, 0.f)});
    h1.h[3] = __float22bfloat162_rn(
        float2{fmaxf(a1.z + r1.z, 0.f), fmaxf(a1.w + r1.w, 0.f)});

    // W2^T A-frags from global (L1-resident, identical for every wave)
#pragma unroll
    for (int tm = 0; tm < 8; ++tm) {
      const bf16x8 wv = *(const bf16x8*)(w2p + (tm << 11) + (kt << 5));
      acc[tm][0] = __builtin_amdgcn_mfma_f32_16x16x32_bf16(
          wv, h0.v, acc[tm][0], 0, 0, 0);
      acc[tm][1] = __builtin_amdgcn_mfma_f32_16x16x32_bf16(
          wv, h1.v, acc[tm][1], 0, 0, 0);
    }
  }

  // epilogue: per lane sum over its 32 w2cols (tm x p), cols = 16tm+4g+p
  float p0 = 0.f, p1 = 0.f;
#pragma unroll
  for (int tm = 0; tm < 8; ++tm) {
    const f32x4 wq = *(const f32x4*)(w3 + (tm << 4) + (g << 2));
#pragma unroll
    for (int p = 0; p < 4; ++p) {
      p0 = fmaf(fmaxf(acc[tm][0][p], 0.f), wq[p], p0);
      p1 = fmaf(fmaxf(acc[tm][1][p], 0.f), wq[p], p1);
    }
  }
  // reduce over the 4 g-groups (w2col bits 2..3): lanes c equal, g differ
  p0 += __shfl_xor(p0, 16);
  p0 += __shfl_xor(p0, 32);
  p1 += __shfl_xor(p1, 16);
  p1 += __shfl_xor(p1, 32);

  if (lane < 32) {
    const float v = (lane < 16 ? p0 : p1) + b3[0];
    out[(b << 12) + (i << 6) + j0 + (lane & 31)] = 1.f / (1.f + __expf(-v));
  }
}

extern "C" void kernel_launch(void* const* d_in, const int* in_sizes, int n_in,
                              void* d_out, int out_size, void* d_ws,
                              size_t ws_size, hipStream_t stream)
{
  const float* af = (const float*)d_in[0];   // (128,64,128)
  const float* W1 = (const float*)d_in[1];   // (128,128)
  const float* b1 = (const float*)d_in[2];   // (128,)
  const float* W2 = (const float*)d_in[3];   // (128,128)
  const float* b2 = (const float*)d_in[4];   // (128,)
  const float* w3 = (const float*)d_in[5];   // (128,)
  const float* b3 = (const float*)d_in[6];   // (1,)
  const float* mw = (const float*)d_in[7];   // (64,)
  float* out = (float*)d_out;                // 524288 corr + 64 weights

  float* AiP = (float*)d_ws;                           // 4 MB
  float* Aj  = AiP + B_SZ * N_SZ * H_SZ;               // 4 MB
  unsigned short* W2T = (unsigned short*)(Aj + B_SZ * N_SZ * H_SZ);  // 32 KB

  setup_kernel<<<2113, 256, 0, stream>>>(af, W1, b1, W2, mw, AiP, Aj, W2T,
                                         out + B_SZ * N_SZ * N_SZ);
  // 16384 waves (1 per 32-row strip) in 4096 blocks of 4 waves, no LDS
  corr_kernel<<<4096, 256, 0, stream>>>(AiP, Aj, W2T, b2, w3, b3, out);
}

// Round 4
// 102.758 us; speedup vs baseline: 1.7974x; 1.7974x over previous
//
#include <hip/hip_runtime.h>
#include <hip/hip_bf16.h>

// CorrelationNetwork fused kernels for MI355X (gfx950) — round 4.
// R3 post-mortem: lane-strided global gathers for MFMA frags cost 64 L1
// transactions per wave-load (~82us of TA time). Law: fragments must come
// from LDS; global accesses must be coalesced. R4: persistent blocks
// (512 blocks x 512 thr, 2/CU), W2 staged to LDS ONCE per block, h1 tile
// built in LDS from coalesced loads, swapped-role MFMA (D[w2col][h1row])
// keeps the epilogue in-lane + tiny LDS combine. b2 folded into acc init.

typedef __bf16 bf16x8 __attribute__((ext_vector_type(8)));
typedef float f32x4 __attribute__((ext_vector_type(4)));

#define B_SZ 128
#define N_SZ 64
#define H_SZ 128

__device__ __forceinline__ unsigned pack_bf16x2(float lo, float hi) {
  unsigned a = __float_as_uint(lo);
  unsigned b = __float_as_uint(hi);
  a += 0x7fffu + ((a >> 16) & 1u);   // RNE round to bf16
  b += 0x7fffu + ((b >> 16) & 1u);
  return (a >> 16) | (b & 0xffff0000u);
}

// ---- setup: blocks 0..2047 prepass (4 bn-rows each), 2048..2111 W2->W2T bf16,
//      block 2112 softmax(mixing_weights)
__global__ __launch_bounds__(256) void setup_kernel(
    const float* __restrict__ af, const float* __restrict__ W1,
    const float* __restrict__ b1, const float* __restrict__ W2,
    const float* __restrict__ mw, float* __restrict__ AiP,
    float* __restrict__ Aj, unsigned short* __restrict__ W2T,
    float* __restrict__ outw)
{
  const int blk = blockIdx.x;
  const int tid = threadIdx.x;

  if (blk < 2048) {
    // prepass: AiP[bn,h] = sum_f f[bn,f]*W1[f,h] + b1[h]; Aj via W1[64+f]
    __shared__ float fl[4 * 64];
    const int bn0 = blk << 2;
    fl[tid] = af[((bn0 + (tid >> 6)) << 7) + (tid & 63)];
    __syncthreads();
    const int h    = tid & 127;
    const int half = tid >> 7;                 // 0 -> Ai, 1 -> Aj
    const float* Wp = W1 + ((half << 6) << 7) + h;
    float acc0 = 0.f, acc1 = 0.f, acc2 = 0.f, acc3 = 0.f;
#pragma unroll
    for (int fq = 0; fq < 16; ++fq) {
      const float w0 = Wp[(fq * 4 + 0) << 7];
      const float w1v = Wp[(fq * 4 + 1) << 7];
      const float w2v = Wp[(fq * 4 + 2) << 7];
      const float w3v = Wp[(fq * 4 + 3) << 7];
      const float4 f0 = *(const float4*)&fl[0 * 64 + (fq << 2)];
      const float4 f1 = *(const float4*)&fl[1 * 64 + (fq << 2)];
      const float4 f2 = *(const float4*)&fl[2 * 64 + (fq << 2)];
      const float4 f3 = *(const float4*)&fl[3 * 64 + (fq << 2)];
      acc0 = fmaf(f0.x, w0, fmaf(f0.y, w1v, fmaf(f0.z, w2v, fmaf(f0.w, w3v, acc0))));
      acc1 = fmaf(f1.x, w0, fmaf(f1.y, w1v, fmaf(f1.z, w2v, fmaf(f1.w, w3v, acc1))));
      acc2 = fmaf(f2.x, w0, fmaf(f2.y, w1v, fmaf(f2.z, w2v, fmaf(f2.w, w3v, acc2))));
      acc3 = fmaf(f3.x, w0, fmaf(f3.y, w1v, fmaf(f3.z, w2v, fmaf(f3.w, w3v, acc3))));
    }
    if (half == 0) {
      const float bb = b1[h];
      AiP[((bn0 + 0) << 7) + h] = acc0 + bb;
      AiP[((bn0 + 1) << 7) + h] = acc1 + bb;
      AiP[((bn0 + 2) << 7) + h] = acc2 + bb;
      AiP[((bn0 + 3) << 7) + h] = acc3 + bb;
    } else {
      Aj[((bn0 + 0) << 7) + h] = acc0;
      Aj[((bn0 + 1) << 7) + h] = acc1;
      Aj[((bn0 + 2) << 7) + h] = acc2;
      Aj[((bn0 + 3) << 7) + h] = acc3;
    }
  } else if (blk < 2112) {
    // W2 (128x128, k-major) -> W2T (n-major) bf16
    int idx = ((blk - 2048) << 8) + tid;       // 0..16383
    int k = idx >> 7, n = idx & 127;
    unsigned u = __float_as_uint(W2[idx]);
    u += 0x7fffu + ((u >> 16) & 1u);
    W2T[(n << 7) + k] = (unsigned short)(u >> 16);
  } else {
    // softmax over 64 mixing weights
    if (tid < 64) {
      float v = mw[tid];
      float m = v;
      for (int off = 32; off > 0; off >>= 1) m = fmaxf(m, __shfl_xor(m, off));
      float e = expf(v - m);
      float s = e;
      for (int off = 32; off > 0; off >>= 1) s += __shfl_xor(s, off);
      outw[tid] = e / s;
    }
  }
}

// ---- main kernel (persistent): 512 blocks x 512 thr, block = (b, 8 ip's).
// Per tile (b, ip): 128 rows r -> i = 2*ip + r/64, j = r%64; full 128 cols.
// Waves: wm = wave&1 (w2col half), wn = wave>>1 (row quarter, 32 rows).
// MFMA swapped roles: D = W2frag(A) * h1frag(B) -> D[m=w2col][n=h1row].
// All frags from swizzled LDS (chunk e' = e ^ (row&15)); W2 staged once.
__global__ __launch_bounds__(512, 4) void corr_kernel(
    const float* __restrict__ AiP, const float* __restrict__ Aj,
    const unsigned short* __restrict__ W2T,
    const float* __restrict__ b2, const float* __restrict__ w3,
    const float* __restrict__ b3, float* __restrict__ out)
{
  __shared__ __align__(16) unsigned short W2s[128 * 128];  // 32 KB
  __shared__ __align__(16) unsigned short At[128 * 128];   // 32 KB
  __shared__ float part[256];                              // [row][wm]

  const int tid  = threadIdx.x;
  const int lane = tid & 63;
  const int wave = tid >> 6;            // 0..7
  const int c = lane & 15, g = lane >> 4;
  const int wm = wave & 1;              // w2col half (64 cols)
  const int wn = wave >> 1;             // row quarter (32 rows)

  const int blk = blockIdx.x;
  const int b   = blk >> 2;             // 0..127
  const int ip0 = (blk & 3) << 3;       // this block's 8 i-pairs

  // ---- stage W2T -> W2s swizzled, once per block (coalesced reads)
  {
    const uint4* src = (const uint4*)W2T;     // 2048 x 16B chunks
#pragma unroll
    for (int it = 0; it < 4; ++it) {
      const int idx = (it << 9) + tid;        // 0..2047
      const int n = idx >> 4, e = idx & 15;
      const uint4 v = src[idx];
      *(uint4*)&W2s[(n << 7) + ((e ^ (n & 15)) << 3)] = v;
    }
  }

  // per-wave b2/w3 slices: w2col = 64*wm + 16*tm + 4*g + p
  f32x4 b2v[4], w3v[4];
#pragma unroll
  for (int tm = 0; tm < 4; ++tm) {
    b2v[tm] = *(const f32x4*)(b2 + (wm << 6) + (tm << 4) + (g << 2));
    w3v[tm] = *(const f32x4*)(w3 + (wm << 6) + (tm << 4) + (g << 2));
  }
  const float bias3 = b3[0];

  const float* AjB = Aj + ((b << 6) << 7);    // this b's 64 Aj rows

  // build-phase thread mapping
  const int kq = tid & 31;                    // float4 column
  const int rr = tid >> 5;                    // 0..15
  const int be = kq >> 1, hf = kq & 1;

  for (int t = 0; t < 8; ++t) {
    const int i0 = (ip0 + t) << 1;
    const float* AiB = AiP + (((b << 6) + i0) << 7);

    __syncthreads();   // prev iter's At reads + part reads done

    // ---- build h1 tile -> At (bf16, swizzled), coalesced global reads
#pragma unroll
    for (int pass = 0; pass < 8; ++pass) {
      const int r = (pass << 4) + rr;
      const float4 a4 = ((const float4*)(AiB + ((r >> 6) << 7)))[kq];
      const float4 c4 = ((const float4*)(AjB + ((r & 63) << 7)))[kq];
      uint2 val;
      val.x = pack_bf16x2(fmaxf(a4.x + c4.x, 0.f), fmaxf(a4.y + c4.y, 0.f));
      val.y = pack_bf16x2(fmaxf(a4.z + c4.z, 0.f), fmaxf(a4.w + c4.w, 0.f));
      *(uint2*)&At[(r << 7) + ((be ^ (r & 15)) << 3) + (hf << 2)] = val;
    }

    __syncthreads();

    // ---- MFMA: acc init = b2 (D = A*B + C)
    f32x4 acc[4][2];
#pragma unroll
    for (int tm = 0; tm < 4; ++tm) {
      acc[tm][0] = b2v[tm];
      acc[tm][1] = b2v[tm];
    }

#pragma unroll
    for (int kt = 0; kt < 4; ++kt) {
      const int es = ((kt << 2) + g) ^ c;     // swizzled chunk (row low4 == c)
      bf16x8 wv[4], hv[2];
#pragma unroll
      for (int tm = 0; tm < 4; ++tm)
        wv[tm] = *(const bf16x8*)&W2s[(((wm << 6) + (tm << 4) + c) << 7) + (es << 3)];
#pragma unroll
      for (int tn = 0; tn < 2; ++tn)
        hv[tn] = *(const bf16x8*)&At[(((wn << 5) + (tn << 4) + c) << 7) + (es << 3)];
#pragma unroll
      for (int tm = 0; tm < 4; ++tm)
#pragma unroll
        for (int tn = 0; tn < 2; ++tn)
          acc[tm][tn] = __builtin_amdgcn_mfma_f32_16x16x32_bf16(
              wv[tm], hv[tn], acc[tm][tn], 0, 0, 0);
    }

    // ---- epilogue: in-lane over (tm,p), shfl over g, LDS combine over wm
    float s0 = 0.f, s1 = 0.f;
#pragma unroll
    for (int tm = 0; tm < 4; ++tm) {
#pragma unroll
      for (int p = 0; p < 4; ++p) {
        s0 = fmaf(fmaxf(acc[tm][0][p], 0.f), w3v[tm][p], s0);
        s1 = fmaf(fmaxf(acc[tm][1][p], 0.f), w3v[tm][p], s1);
      }
    }
    s0 += __shfl_xor(s0, 16);
    s0 += __shfl_xor(s0, 32);
    s1 += __shfl_xor(s1, 16);
    s1 += __shfl_xor(s1, 32);
    if (g == 0) {                              // 16 lanes, conflict-free
      part[(((wn << 5) + c) << 1) + wm]      = s0;
      part[(((wn << 5) + 16 + c) << 1) + wm] = s1;
    }

    __syncthreads();

    if (tid < 128) {
      const float2 pp = *(const float2*)&part[tid << 1];
      const float v = pp.x + pp.y + bias3;
      out[(b << 12) + (i0 << 6) + tid] = 1.f / (1.f + __expf(-v));
    }
  }
}

extern "C" void kernel_launch(void* const* d_in, const int* in_sizes, int n_in,
                              void* d_out, int out_size, void* d_ws,
                              size_t ws_size, hipStream_t stream)
{
  const float* af = (const float*)d_in[0];   // (128,64,128)
  const float* W1 = (const float*)d_in[1];   // (128,128)
  const float* b1 = (const float*)d_in[2];   // (128,)
  const float* W2 = (const float*)d_in[3];   // (128,128)
  const float* b2 = (const float*)d_in[4];   // (128,)
  const float* w3 = (const float*)d_in[5];   // (128,)
  const float* b3 = (const float*)d_in[6];   // (1,)
  const float* mw = (const float*)d_in[7];   // (64,)
  float* out = (float*)d_out;                // 524288 corr + 64 weights

  float* AiP = (float*)d_ws;                           // 4 MB
  float* Aj  = AiP + B_SZ * N_SZ * H_SZ;               // 4 MB
  unsigned short* W2T = (unsigned short*)(Aj + B_SZ * N_SZ * H_SZ);  // 32 KB

  setup_kernel<<<2113, 256, 0, stream>>>(af, W1, b1, W2, mw, AiP, Aj, W2T,
                                         out + B_SZ * N_SZ * N_SZ);
  // persistent: 512 blocks (2/CU), each owns 8 (b, i-pair) tiles
  corr_kernel<<<512, 512, 0, stream>>>(AiP, Aj, W2T, b2, w3, b3, out);
}